// Round 1
// baseline (2401.925 us; speedup 1.0000x reference)
//
#include <hip/hip_runtime.h>

typedef _Float16 half8 __attribute__((ext_vector_type(8)));
typedef _Float16 half4v __attribute__((ext_vector_type(4)));
typedef float f32x4 __attribute__((ext_vector_type(4)));

__device__ __forceinline__ void gload16(const _Float16* g, _Float16* l) {
  __builtin_amdgcn_global_load_lds((const __attribute__((address_space(1))) void*)g,
                                   (__attribute__((address_space(3))) void*)l, 16, 0, 0);
}

// ---------------------------------------------------------------------------
// fp32 -> fp16 cast (n multiple of 4)
__global__ __launch_bounds__(256) void cast_k(const float* __restrict__ in,
                                              _Float16* __restrict__ out, int n) {
  int i = (blockIdx.x * 256 + threadIdx.x) << 2;
  if (i < n) {
    float4 v = *(const float4*)(in + i);
    half4v h;
    h[0] = (_Float16)v.x; h[1] = (_Float16)v.y; h[2] = (_Float16)v.z; h[3] = (_Float16)v.w;
    *(half4v*)(out + i) = h;
  }
}

// ---------------------------------------------------------------------------
// W[K][N] fp32 -> WT[N][K] fp16, batched over blockIdx.z (stride K*N both sides)
__global__ __launch_bounds__(256) void tcast_k(const float* __restrict__ W,
                                               _Float16* __restrict__ WT, int K, int N) {
  __shared__ float tile[32][33];
  const size_t zo = (size_t)blockIdx.z * K * N;
  const int n0 = blockIdx.x << 5, k0 = blockIdx.y << 5;
  const int tx = threadIdx.x & 31, ty = threadIdx.x >> 5;  // 32 x 8
#pragma unroll
  for (int i = 0; i < 4; i++)
    tile[ty + i * 8][tx] = W[zo + (size_t)(k0 + ty + i * 8) * N + n0 + tx];
  __syncthreads();
#pragma unroll
  for (int i = 0; i < 4; i++)
    WT[zo + (size_t)(n0 + ty + i * 8) * K + k0 + tx] = (_Float16)tile[tx][ty + i * 8];
}

// ---------------------------------------------------------------------------
// NT GEMM: C[M,N] = epilogue(A[M,K] @ Bt[N,K]^T + bias)
// 128x128 tile, BK=32, 256 thr = 4 waves (2x2), each wave 64x64 via 4x4 mfma 16x16x32.
// MODE: 0 relu->H | 1 tanh->H | 2 bias->H | 3 +pos->F | 4 gelu->H | 5 +aux->F&H | 6 ->F
template <int MODE>
__global__ __launch_bounds__(256) void gemm_nt(const _Float16* __restrict__ A,
                                               const _Float16* __restrict__ Bt,
                                               const float* __restrict__ bias,
                                               _Float16* __restrict__ outH,
                                               float* __restrict__ outF,
                                               const float* __restrict__ aux,
                                               int M, int N, int K) {
  __shared__ __align__(16) _Float16 As[128 * 32];
  __shared__ __align__(16) _Float16 Bs[128 * 32];
  const int tid = threadIdx.x;
  const int lane = tid & 63, w = tid >> 6;
  const int wr = (w >> 1) << 6, wc = (w & 1) << 6;
  const int lr = lane & 15, quad = lane >> 4;
  const int mb = blockIdx.y << 7, nb = blockIdx.x << 7;

  const int c0 = tid, c1 = tid + 256;
  const _Float16* ga0 = A + (size_t)(mb + (c0 >> 2)) * K + ((c0 & 3) << 3);
  const _Float16* ga1 = A + (size_t)(mb + (c1 >> 2)) * K + ((c1 & 3) << 3);
  const _Float16* gb0 = Bt + (size_t)(nb + (c0 >> 2)) * K + ((c0 & 3) << 3);
  const _Float16* gb1 = Bt + (size_t)(nb + (c1 >> 2)) * K + ((c1 & 3) << 3);
  _Float16* la0 = As + c0 * 8;
  _Float16* la1 = As + c1 * 8;
  _Float16* lb0 = Bs + c0 * 8;
  _Float16* lb1 = Bs + c1 * 8;

  f32x4 acc[4][4] = {};

  for (int k0 = 0; k0 < K; k0 += 32) {
    gload16(ga0 + k0, la0);
    gload16(ga1 + k0, la1);
    gload16(gb0 + k0, lb0);
    gload16(gb1 + k0, lb1);
    __syncthreads();  // drains vmcnt for global_load_lds
    half8 af[4], bf[4];
    const _Float16* ap = As + (wr + lr) * 32 + (quad << 3);
    const _Float16* bp = Bs + (wc + lr) * 32 + (quad << 3);
#pragma unroll
    for (int i = 0; i < 4; i++) {
      af[i] = *(const half8*)(ap + i * 512);
      bf[i] = *(const half8*)(bp + i * 512);
    }
#pragma unroll
    for (int mt = 0; mt < 4; mt++)
#pragma unroll
      for (int nt = 0; nt < 4; nt++)
        acc[mt][nt] = __builtin_amdgcn_mfma_f32_16x16x32_f16(af[mt], bf[nt], acc[mt][nt], 0, 0, 0);
    __syncthreads();  // protect LDS before next stage
  }

  // C/D layout: col = lane&15, row = (lane>>4)*4 + reg  (verified, dtype-independent)
#pragma unroll
  for (int nt = 0; nt < 4; nt++) {
    const int col = nb + wc + (nt << 4) + lr;
    const float bv = bias[col];
#pragma unroll
    for (int mt = 0; mt < 4; mt++) {
      const int row0 = mb + wr + (mt << 4) + (quad << 2);
#pragma unroll
      for (int r = 0; r < 4; r++) {
        const int row = row0 + r;
        const size_t off = (size_t)row * N + col;
        float v = acc[mt][nt][r] + bv;
        if (MODE == 0) {
          outH[off] = (_Float16)fmaxf(v, 0.0f);
        } else if (MODE == 1) {
          outH[off] = (_Float16)tanhf(v);
        } else if (MODE == 2) {
          outH[off] = (_Float16)v;
        } else if (MODE == 3) {
          outF[off] = v + aux[(size_t)(row & 511) * N + col];  // + pos_w[s]
        } else if (MODE == 4) {
          outH[off] = (_Float16)(0.5f * v * (1.0f + erff(v * 0.70710678118654752f)));
        } else if (MODE == 5) {
          float xv = aux[off] + v;  // residual add
          outF[off] = xv;
          outH[off] = (_Float16)xv;
        } else {
          outF[off] = v;
        }
      }
    }
  }
}

// ---------------------------------------------------------------------------
// LayerNorm over D=256; 4 rows/block (wave per row). xn = fp16(LN(x))
__global__ __launch_bounds__(256) void ln_k(const float* __restrict__ x,
                                            const float* __restrict__ g,
                                            const float* __restrict__ b,
                                            _Float16* __restrict__ xn) {
  const int w = threadIdx.x >> 6, lane = threadIdx.x & 63;
  const int row = (blockIdx.x << 2) + w;
  const size_t base = ((size_t)row << 8) + (lane << 2);
  float4 v = *(const float4*)(x + base);
  float s = v.x + v.y + v.z + v.w;
  float sq = v.x * v.x + v.y * v.y + v.z * v.z + v.w * v.w;
#pragma unroll
  for (int o = 32; o; o >>= 1) { s += __shfl_xor(s, o); sq += __shfl_xor(sq, o); }
  const float mean = s * 0.00390625f;
  const float rs = rsqrtf(sq * 0.00390625f - mean * mean + 1e-5f);
  const int c = lane << 2;
  float4 gv = *(const float4*)(g + c);
  float4 bv = *(const float4*)(b + c);
  half4v o4;
  o4[0] = (_Float16)((v.x - mean) * rs * gv.x + bv.x);
  o4[1] = (_Float16)((v.y - mean) * rs * gv.y + bv.y);
  o4[2] = (_Float16)((v.z - mean) * rs * gv.z + bv.z);
  o4[3] = (_Float16)((v.w - mean) * rs * gv.w + bv.w);
  *(half4v*)(xn + base) = o4;
}

// x' = LN(x + a); writes x' fp32 (new residual) and fp16 copy
__global__ __launch_bounds__(256) void add_ln_k(const float* __restrict__ x,
                                                const float* __restrict__ a,
                                                const float* __restrict__ g,
                                                const float* __restrict__ b,
                                                float* __restrict__ xo,
                                                _Float16* __restrict__ xn) {
  const int w = threadIdx.x >> 6, lane = threadIdx.x & 63;
  const int row = (blockIdx.x << 2) + w;
  const size_t base = ((size_t)row << 8) + (lane << 2);
  float4 v = *(const float4*)(x + base);
  float4 av = *(const float4*)(a + base);
  v.x += av.x; v.y += av.y; v.z += av.z; v.w += av.w;
  float s = v.x + v.y + v.z + v.w;
  float sq = v.x * v.x + v.y * v.y + v.z * v.z + v.w * v.w;
#pragma unroll
  for (int o = 32; o; o >>= 1) { s += __shfl_xor(s, o); sq += __shfl_xor(sq, o); }
  const float mean = s * 0.00390625f;
  const float rs = rsqrtf(sq * 0.00390625f - mean * mean + 1e-5f);
  const int c = lane << 2;
  float4 gv = *(const float4*)(g + c);
  float4 bv = *(const float4*)(b + c);
  float4 o4;
  o4.x = (v.x - mean) * rs * gv.x + bv.x;
  o4.y = (v.y - mean) * rs * gv.y + bv.y;
  o4.z = (v.z - mean) * rs * gv.z + bv.z;
  o4.w = (v.w - mean) * rs * gv.w + bv.w;
  *(float4*)(xo + base) = o4;
  half4v h;
  h[0] = (_Float16)o4.x; h[1] = (_Float16)o4.y; h[2] = (_Float16)o4.z; h[3] = (_Float16)o4.w;
  *(half4v*)(xn + base) = h;
}

// ---------------------------------------------------------------------------
// Causal flash attention (VALU). Block = (b,h,qtile of 128 rows), 256 threads:
// thread (half, tr) owns q-row tr, processes kv-tiles of parity `half`, merge via LDS.
__global__ __launch_bounds__(256) void attn_k(const _Float16* __restrict__ qkv,
                                              float* __restrict__ aout) {
  __shared__ float Ks[64][32];
  __shared__ float Vs[64][32];
  __shared__ float Om[128];
  __shared__ float Ol[128];
  __shared__ float Os[128][32];
  const int bid = blockIdx.x;  // b*32 + h*4 + qt
  const int qt = bid & 3, h = (bid >> 2) & 7, b = bid >> 5;
  const int q0 = qt << 7;
  const int t = threadIdx.x, hf = t >> 7, tr = t & 127;
  const int q = q0 + tr;
  const _Float16* qrow = qkv + ((size_t)(b * 512 + q)) * 768 + h * 32;
  float qv[32];
#pragma unroll
  for (int i = 0; i < 4; i++) {
    half8 hh = ((const half8*)qrow)[i];
#pragma unroll
    for (int j = 0; j < 8; j++) qv[i * 8 + j] = (float)hh[j];
  }
  float O[32];
#pragma unroll
  for (int d = 0; d < 32; d++) O[d] = 0.0f;
  float m = -1e30f, lsum = 0.0f;
  const int nkt = (q0 + 128) >> 6;
  const int srow = t >> 2, soff = (t & 3) << 3;
  for (int kt = 0; kt < nkt; kt++) {
    const int kb = kt << 6;
    __syncthreads();
    {  // stage 64x32 K and V (fp32) cooperatively
      const _Float16* kp = qkv + ((size_t)(b * 512 + kb + srow)) * 768 + 256 + h * 32 + soff;
      half8 hk = *(const half8*)kp;
      half8 hv = *(const half8*)(kp + 256);
#pragma unroll
      for (int j = 0; j < 8; j++) {
        Ks[srow][soff + j] = (float)hk[j];
        Vs[srow][soff + j] = (float)hv[j];
      }
    }
    __syncthreads();
    if ((((kt ^ hf) & 1) == 0) && kb <= q) {
      for (int j0 = 0; j0 < 64; j0 += 8) {
        if (kb + j0 > q) break;
        float s[8];
        float mx = -1e30f;
#pragma unroll
        for (int jj = 0; jj < 8; jj++) {
          const float4* kr = (const float4*)Ks[j0 + jj];
          float a0 = 0, a1 = 0, a2 = 0, a3 = 0;
#pragma unroll
          for (int d4 = 0; d4 < 8; d4++) {
            float4 kk = kr[d4];
            a0 = fmaf(qv[d4 * 4 + 0], kk.x, a0);
            a1 = fmaf(qv[d4 * 4 + 1], kk.y, a1);
            a2 = fmaf(qv[d4 * 4 + 2], kk.z, a2);
            a3 = fmaf(qv[d4 * 4 + 3], kk.w, a3);
          }
          float sc = (a0 + a1) + (a2 + a3);
          s[jj] = (kb + j0 + jj <= q) ? sc * 0.17677669529663687f : -1e30f;
          mx = fmaxf(mx, s[jj]);
        }
        const float mn = fmaxf(m, mx);
        const float corr = __expf(m - mn);
        lsum *= corr;
#pragma unroll
        for (int d = 0; d < 32; d++) O[d] *= corr;
        m = mn;
#pragma unroll
        for (int jj = 0; jj < 8; jj++) {
          const float p = __expf(s[jj] - m);
          lsum += p;
          const float4* vr = (const float4*)Vs[j0 + jj];
#pragma unroll
          for (int d4 = 0; d4 < 8; d4++) {
            float4 vv = vr[d4];
            O[d4 * 4 + 0] = fmaf(p, vv.x, O[d4 * 4 + 0]);
            O[d4 * 4 + 1] = fmaf(p, vv.y, O[d4 * 4 + 1]);
            O[d4 * 4 + 2] = fmaf(p, vv.z, O[d4 * 4 + 2]);
            O[d4 * 4 + 3] = fmaf(p, vv.w, O[d4 * 4 + 3]);
          }
        }
      }
    }
  }
  __syncthreads();
  if (hf) {
    Om[tr] = m;
    Ol[tr] = lsum;
#pragma unroll
    for (int d = 0; d < 32; d++) Os[tr][d] = O[d];
  }
  __syncthreads();
  if (!hf) {
    const float m1 = Om[tr], l1 = Ol[tr];
    const float mn = fmaxf(m, m1);
    const float c0 = __expf(m - mn), c1 = __expf(m1 - mn);
    const float linv = 1.0f / (lsum * c0 + l1 * c1);
    float* op = aout + ((size_t)(b * 512 + q)) * 256 + h * 32;
#pragma unroll
    for (int d = 0; d < 32; d++) op[d] = (O[d] * c0 + Os[tr][d] * c1) * linv;
  }
}

// ---------------------------------------------------------------------------
// Global mean/sumsq reduction and standardization
__global__ __launch_bounds__(256) void reduce_stats_k(const float4* __restrict__ v, int n4,
                                                      float* __restrict__ stats) {
  float s = 0.0f, sq = 0.0f;
  for (int i = blockIdx.x * 256 + threadIdx.x; i < n4; i += gridDim.x * 256) {
    float4 x = v[i];
    s += x.x + x.y + x.z + x.w;
    sq += x.x * x.x + x.y * x.y + x.z * x.z + x.w * x.w;
  }
#pragma unroll
  for (int o = 32; o; o >>= 1) { s += __shfl_xor(s, o); sq += __shfl_xor(sq, o); }
  __shared__ float ss[4], sqq[4];
  const int w = threadIdx.x >> 6;
  if ((threadIdx.x & 63) == 0) { ss[w] = s; sqq[w] = sq; }
  __syncthreads();
  if (threadIdx.x == 0) {
    atomicAdd(&stats[0], ss[0] + ss[1] + ss[2] + ss[3]);
    atomicAdd(&stats[1], sqq[0] + sqq[1] + sqq[2] + sqq[3]);
  }
}

__global__ __launch_bounds__(256) void finalize_k(const float4* __restrict__ enc,
                                                  const float* __restrict__ stats,
                                                  float4* __restrict__ out, int n4, float n) {
  const int i = blockIdx.x * 256 + threadIdx.x;
  if (i >= n4) return;
  const float s = stats[0], q = stats[1];
  const float mean = s / n;
  const float var = (q - s * s / n) / (n - 1.0f);  // ddof=1
  const float inv = rsqrtf(var);
  float4 x = enc[i];
  float4 o;
  o.x = (x.x - mean) * inv + 1e-10f;
  o.y = (x.y - mean) * inv + 1e-10f;
  o.z = (x.z - mean) * inv + 1e-10f;
  o.w = (x.w - mean) * inv + 1e-10f;
  out[i] = o;
}

// ---------------------------------------------------------------------------
extern "C" void kernel_launch(void* const* d_in, const int* in_sizes, int n_in,
                              void* d_out, int out_size, void* d_ws, size_t ws_size,
                              hipStream_t stream) {
  const float* state = (const float*)d_in[0];
  const float* fc1_w = (const float*)d_in[1];
  const float* fc1_b = (const float*)d_in[2];
  const float* fc2_w = (const float*)d_in[3];
  const float* fc2_b = (const float*)d_in[4];
  const float* fc3_w = (const float*)d_in[5];
  const float* fc3_b = (const float*)d_in[6];
  const float* fc4_w = (const float*)d_in[7];
  const float* fc4_b = (const float*)d_in[8];
  const float* fc5_w = (const float*)d_in[9];
  const float* fc5_b = (const float*)d_in[10];
  const float* pre_w = (const float*)d_in[11];
  const float* pre_b = (const float*)d_in[12];
  const float* pos_w = (const float*)d_in[13];
  const float* enc_w = (const float*)d_in[14];
  const float* enc_b = (const float*)d_in[15];
  const float* ln1_g = (const float*)d_in[16];
  const float* ln1_b = (const float*)d_in[17];
  const float* ln2_g = (const float*)d_in[18];
  const float* ln2_b = (const float*)d_in[19];
  const float* res_w1 = (const float*)d_in[20];
  const float* res_b1 = (const float*)d_in[21];
  const float* res_w2 = (const float*)d_in[22];
  const float* res_b2 = (const float*)d_in[23];
  const float* out_w = (const float*)d_in[24];
  const float* out_b = (const float*)d_in[25];

  char* ws = (char*)d_ws;
  // big regions: wbuf 33.5MB | bufA 33.5MB | bufB 33.5MB   (~100.7 MB total)
  _Float16* wbuf = (_Float16*)ws;
  _Float16* bufA = (_Float16*)(ws + 33554432);
  _Float16* bufB = (_Float16*)(ws + 67108864);
  // sub-allocations inside bufA (live only after trunk):
  _Float16* xn16 = bufA;                         // 4096*256
  _Float16* qkv16 = bufA + 1048576;              // 4096*768
  _Float16* h16 = bufA + 4194304;                // 4096*1024
  _Float16* x16 = bufA + 8388608;                // 4096*256
  // sub-allocations inside bufB (clear of a5 @ [0,2MB) and a1/a3 lifetimes):
  float* xres = (float*)(ws + 67108864 + 4194304);   // 4096*256 fp32
  float* aout = xres + 1048576;                      // 4096*256 fp32
  float* enc32 = aout + 1048576;                     // 4096*128 fp32
  float* stats = enc32 + 524288;                     // 2 floats
  // block-weight transposes (fp16), inside bufB at +16MB:
  _Float16* encT = (_Float16*)(ws + 67108864 + 16777216);  // 8*768*256
  _Float16* res1T = encT + 1572864;                        // 8*1024*256
  _Float16* res2T = res1T + 2097152;                       // 8*256*1024
  _Float16* outT = res2T + 2097152;                        // 128*256

  const dim3 tb(256);

  // ---- trunk ----
  cast_k<<<16384, tb, 0, stream>>>(state, bufA, 16777216);
  tcast_k<<<dim3(128, 128, 1), tb, 0, stream>>>(fc1_w, wbuf, 4096, 4096);
  gemm_nt<0><<<dim3(32, 32), tb, 0, stream>>>(bufA, wbuf, fc1_b, bufB, nullptr, nullptr, 4096, 4096, 4096);
  tcast_k<<<dim3(64, 128, 1), tb, 0, stream>>>(fc2_w, wbuf, 4096, 2048);
  gemm_nt<0><<<dim3(16, 32), tb, 0, stream>>>(bufB, wbuf, fc2_b, bufA, nullptr, nullptr, 4096, 2048, 4096);
  tcast_k<<<dim3(32, 64, 1), tb, 0, stream>>>(fc3_w, wbuf, 2048, 1024);
  gemm_nt<0><<<dim3(8, 32), tb, 0, stream>>>(bufA, wbuf, fc3_b, bufB, nullptr, nullptr, 4096, 1024, 2048);
  tcast_k<<<dim3(16, 32, 1), tb, 0, stream>>>(fc4_w, wbuf, 1024, 512);
  gemm_nt<0><<<dim3(4, 32), tb, 0, stream>>>(bufB, wbuf, fc4_b, bufA, nullptr, nullptr, 4096, 512, 1024);
  tcast_k<<<dim3(8, 16, 1), tb, 0, stream>>>(fc5_w, wbuf, 512, 256);
  gemm_nt<1><<<dim3(2, 32), tb, 0, stream>>>(bufA, wbuf, fc5_b, bufB, nullptr, nullptr, 4096, 256, 512);
  tcast_k<<<dim3(8, 8, 1), tb, 0, stream>>>(pre_w, wbuf, 256, 256);
  gemm_nt<3><<<dim3(2, 32), tb, 0, stream>>>(bufB, wbuf, pre_b, nullptr, xres, pos_w, 4096, 256, 256);

  // ---- batched block-weight transposes ----
  tcast_k<<<dim3(24, 8, 8), tb, 0, stream>>>(enc_w, encT, 256, 768);
  tcast_k<<<dim3(32, 8, 8), tb, 0, stream>>>(res_w1, res1T, 256, 1024);
  tcast_k<<<dim3(8, 32, 8), tb, 0, stream>>>(res_w2, res2T, 1024, 256);
  tcast_k<<<dim3(4, 8, 1), tb, 0, stream>>>(out_w, outT, 256, 128);

  // ---- transformer blocks ----
  for (int l = 0; l < 8; l++) {
    ln_k<<<1024, tb, 0, stream>>>(xres, ln1_g + l * 256, ln1_b + l * 256, xn16);
    gemm_nt<2><<<dim3(6, 32), tb, 0, stream>>>(xn16, encT + (size_t)l * 196608, enc_b + l * 768,
                                               qkv16, nullptr, nullptr, 4096, 768, 256);
    attn_k<<<256, tb, 0, stream>>>(qkv16, aout);
    add_ln_k<<<1024, tb, 0, stream>>>(xres, aout, ln2_g + l * 256, ln2_b + l * 256, xres, xn16);
    gemm_nt<4><<<dim3(8, 32), tb, 0, stream>>>(xn16, res1T + (size_t)l * 262144, res_b1 + l * 1024,
                                               h16, nullptr, nullptr, 4096, 1024, 256);
    gemm_nt<5><<<dim3(2, 32), tb, 0, stream>>>(h16, res2T + (size_t)l * 262144, res_b2 + l * 256,
                                               x16, xres, xres, 4096, 256, 1024);
  }

  // ---- output projection + global standardization ----
  gemm_nt<6><<<dim3(1, 32), tb, 0, stream>>>(x16, outT, out_b, nullptr, enc32, nullptr, 4096, 128, 256);
  hipMemsetAsync(stats, 0, 2 * sizeof(float), stream);
  reduce_stats_k<<<256, tb, 0, stream>>>((const float4*)enc32, 131072, stats);
  finalize_k<<<512, tb, 0, stream>>>((const float4*)enc32, stats, (float4*)d_out, 131072, 524288.0f);
}

// Round 2
// 1438.326 us; speedup vs baseline: 1.6699x; 1.6699x over previous
//
#include <hip/hip_runtime.h>

typedef _Float16 half8 __attribute__((ext_vector_type(8)));
typedef _Float16 half4v __attribute__((ext_vector_type(4)));
typedef _Float16 half2v __attribute__((ext_vector_type(2)));
typedef float f32x4 __attribute__((ext_vector_type(4)));

__device__ __forceinline__ void gload16(const _Float16* g, _Float16* l) {
  __builtin_amdgcn_global_load_lds((const __attribute__((address_space(1))) void*)g,
                                   (__attribute__((address_space(3))) void*)l, 16, 0, 0);
}

// ---------------------------------------------------------------------------
// fp32 -> fp16 cast (n multiple of 4)
__global__ __launch_bounds__(256) void cast_k(const float* __restrict__ in,
                                              _Float16* __restrict__ out, int n) {
  int i = (blockIdx.x * 256 + threadIdx.x) << 2;
  if (i < n) {
    float4 v = *(const float4*)(in + i);
    half4v h;
    h[0] = (_Float16)v.x; h[1] = (_Float16)v.y; h[2] = (_Float16)v.z; h[3] = (_Float16)v.w;
    *(half4v*)(out + i) = h;
  }
}

// ---------------------------------------------------------------------------
// W[K][N] fp32 -> WT[N][K] fp16, batched over blockIdx.z
__global__ __launch_bounds__(256) void tcast_k(const float* __restrict__ W,
                                               _Float16* __restrict__ WT, int K, int N) {
  __shared__ float tile[32][33];
  const size_t zo = (size_t)blockIdx.z * K * N;
  const int n0 = blockIdx.x << 5, k0 = blockIdx.y << 5;
  const int tx = threadIdx.x & 31, ty = threadIdx.x >> 5;  // 32 x 8
#pragma unroll
  for (int i = 0; i < 4; i++)
    tile[ty + i * 8][tx] = W[zo + (size_t)(k0 + ty + i * 8) * N + n0 + tx];
  __syncthreads();
#pragma unroll
  for (int i = 0; i < 4; i++)
    WT[zo + (size_t)(n0 + ty + i * 8) * K + k0 + tx] = (_Float16)tile[tx][ty + i * 8];
}

// ---------------------------------------------------------------------------
// NT GEMM: C[M,N] = epilogue(A[M,K] @ Bt[N,K]^T + bias), BK=64, XOR-swizzled LDS.
// 256 threads = 4 waves arranged WGM x WGN; wave tile TM x TN via 16x16x32 MFMA.
// LDS chunk swizzle: physical chunk j of row r holds logical chunk j ^ (r&7);
// staging fetches the permuted GLOBAL chunk so global_load_lds stays contiguous
// and fragment ds_read_b128 is 2-way/bank (free).
// MODE: 0 relu->H | 1 tanh->H | 2 bias->H | 3 +pos->F | 4 gelu->H | 5 +aux->F&H | 6 ->F
template <int BM, int BN, int WGM, int WGN, int MODE>
__global__ __launch_bounds__(256) void gemm_nt(const _Float16* __restrict__ A,
                                               const _Float16* __restrict__ Bt,
                                               const float* __restrict__ bias,
                                               _Float16* __restrict__ outH,
                                               float* __restrict__ outF,
                                               const float* __restrict__ aux,
                                               int M, int N, int K) {
  constexpr int BK = 64;
  constexpr int TM = BM / WGM, TN = BN / WGN;
  constexpr int AM = TM / 16, AN = TN / 16;
  constexpr int LA = BM * BK / 2048, LB = BN * BK / 2048;
  __shared__ __align__(16) _Float16 As[BM * BK];
  __shared__ __align__(16) _Float16 Bs[BN * BK];
  const int tid = threadIdx.x;
  const int lane = tid & 63, w = tid >> 6;
  const int wr = (w / WGN) * TM, wc = (w % WGN) * TN;
  const int lr = lane & 15, quad = lane >> 4;
  const int mb = blockIdx.y * BM, nb = blockIdx.x * BN;

  const _Float16* ga[LA];
  const _Float16* gb[LB];
  _Float16* la[LA];
  _Float16* lb[LB];
#pragma unroll
  for (int i = 0; i < LA; i++) {
    const int c = tid + i * 256, row = c >> 3, j = c & 7;
    ga[i] = A + (size_t)(mb + row) * K + ((j ^ (row & 7)) << 3);
    la[i] = As + c * 8;
  }
#pragma unroll
  for (int i = 0; i < LB; i++) {
    const int c = tid + i * 256, row = c >> 3, j = c & 7;
    gb[i] = Bt + (size_t)(nb + row) * K + ((j ^ (row & 7)) << 3);
    lb[i] = Bs + c * 8;
  }

  f32x4 acc[AM][AN] = {};

  for (int k0 = 0; k0 < K; k0 += BK) {
#pragma unroll
    for (int i = 0; i < LA; i++) gload16(ga[i] + k0, la[i]);
#pragma unroll
    for (int i = 0; i < LB; i++) gload16(gb[i] + k0, lb[i]);
    __syncthreads();
#pragma unroll
    for (int ks = 0; ks < 2; ks++) {
      const int pc = (((ks << 2) | quad) ^ (lane & 7)) << 3;  // physical chunk offset
      half8 af[AM], bf[AN];
#pragma unroll
      for (int mt = 0; mt < AM; mt++)
        af[mt] = *(const half8*)(As + (wr + mt * 16 + lr) * BK + pc);
#pragma unroll
      for (int nt = 0; nt < AN; nt++)
        bf[nt] = *(const half8*)(Bs + (wc + nt * 16 + lr) * BK + pc);
#pragma unroll
      for (int mt = 0; mt < AM; mt++)
#pragma unroll
        for (int nt = 0; nt < AN; nt++)
          acc[mt][nt] = __builtin_amdgcn_mfma_f32_16x16x32_f16(af[mt], bf[nt], acc[mt][nt], 0, 0, 0);
    }
    __syncthreads();
  }

  // C/D layout: col = lane&15, row = (lane>>4)*4 + reg
#pragma unroll
  for (int nt = 0; nt < AN; nt++) {
    const int col = nb + wc + (nt << 4) + lr;
    const float bv = bias[col];
#pragma unroll
    for (int mt = 0; mt < AM; mt++) {
      const int row0 = mb + wr + (mt << 4) + (quad << 2);
#pragma unroll
      for (int r = 0; r < 4; r++) {
        const int row = row0 + r;
        const size_t off = (size_t)row * N + col;
        float v = acc[mt][nt][r] + bv;
        if (MODE == 0) {
          outH[off] = (_Float16)fmaxf(v, 0.0f);
        } else if (MODE == 1) {
          outH[off] = (_Float16)tanhf(v);
        } else if (MODE == 2) {
          outH[off] = (_Float16)v;
        } else if (MODE == 3) {
          outF[off] = v + aux[(size_t)(row & 511) * N + col];  // + pos_w[s]
        } else if (MODE == 4) {
          outH[off] = (_Float16)(0.5f * v * (1.0f + erff(v * 0.70710678118654752f)));
        } else if (MODE == 5) {
          float xv = aux[off] + v;  // residual add
          outF[off] = xv;
          outH[off] = (_Float16)xv;
        } else {
          outF[off] = v;
        }
      }
    }
  }
}

// ---------------------------------------------------------------------------
// LayerNorm over D=256; 4 rows/block. xn = fp16(LN(x))
__global__ __launch_bounds__(256) void ln_k(const float* __restrict__ x,
                                            const float* __restrict__ g,
                                            const float* __restrict__ b,
                                            _Float16* __restrict__ xn) {
  const int w = threadIdx.x >> 6, lane = threadIdx.x & 63;
  const int row = (blockIdx.x << 2) + w;
  const size_t base = ((size_t)row << 8) + (lane << 2);
  float4 v = *(const float4*)(x + base);
  float s = v.x + v.y + v.z + v.w;
  float sq = v.x * v.x + v.y * v.y + v.z * v.z + v.w * v.w;
#pragma unroll
  for (int o = 32; o; o >>= 1) { s += __shfl_xor(s, o); sq += __shfl_xor(sq, o); }
  const float mean = s * 0.00390625f;
  const float rs = rsqrtf(sq * 0.00390625f - mean * mean + 1e-5f);
  const int c = lane << 2;
  float4 gv = *(const float4*)(g + c);
  float4 bv = *(const float4*)(b + c);
  half4v o4;
  o4[0] = (_Float16)((v.x - mean) * rs * gv.x + bv.x);
  o4[1] = (_Float16)((v.y - mean) * rs * gv.y + bv.y);
  o4[2] = (_Float16)((v.z - mean) * rs * gv.z + bv.z);
  o4[3] = (_Float16)((v.w - mean) * rs * gv.w + bv.w);
  *(half4v*)(xn + base) = o4;
}

// x' = LN(x + a); writes x' fp32 and fp16 copy
__global__ __launch_bounds__(256) void add_ln_k(const float* __restrict__ x,
                                                const float* __restrict__ a,
                                                const float* __restrict__ g,
                                                const float* __restrict__ b,
                                                float* __restrict__ xo,
                                                _Float16* __restrict__ xn) {
  const int w = threadIdx.x >> 6, lane = threadIdx.x & 63;
  const int row = (blockIdx.x << 2) + w;
  const size_t base = ((size_t)row << 8) + (lane << 2);
  float4 v = *(const float4*)(x + base);
  float4 av = *(const float4*)(a + base);
  v.x += av.x; v.y += av.y; v.z += av.z; v.w += av.w;
  float s = v.x + v.y + v.z + v.w;
  float sq = v.x * v.x + v.y * v.y + v.z * v.z + v.w * v.w;
#pragma unroll
  for (int o = 32; o; o >>= 1) { s += __shfl_xor(s, o); sq += __shfl_xor(sq, o); }
  const float mean = s * 0.00390625f;
  const float rs = rsqrtf(sq * 0.00390625f - mean * mean + 1e-5f);
  const int c = lane << 2;
  float4 gv = *(const float4*)(g + c);
  float4 bv = *(const float4*)(b + c);
  float4 o4;
  o4.x = (v.x - mean) * rs * gv.x + bv.x;
  o4.y = (v.y - mean) * rs * gv.y + bv.y;
  o4.z = (v.z - mean) * rs * gv.z + bv.z;
  o4.w = (v.w - mean) * rs * gv.w + bv.w;
  *(float4*)(xo + base) = o4;
  half4v h;
  h[0] = (_Float16)o4.x; h[1] = (_Float16)o4.y; h[2] = (_Float16)o4.z; h[3] = (_Float16)o4.w;
  *(half4v*)(xn + base) = h;
}

// ---------------------------------------------------------------------------
// Causal flash attention v2. Block = (b, h, 64-row q-tile); 512 blocks.
// Whole causal K/V strip staged fp16 in LDS once (async), then 4-way kv-split
// per q-row with fdot2 scores; partials merged via LDS (aliased over K buffer).
__global__ __launch_bounds__(256) void attn_k(const _Float16* __restrict__ qkv,
                                              float* __restrict__ aout) {
  __shared__ __align__(16) char smem[65536];
  _Float16* Ks = (_Float16*)smem;            // [512][32] fp16, 32KB max
  _Float16* Vs = (_Float16*)(smem + 32768);  // [512][32] fp16, 32KB max
  float* Om = (float*)smem;                  // merge region aliases Ks
  float* Ol = (float*)(smem + 768);
  float* Os = (float*)(smem + 1536);         // [3][64][33]

  const int bid = blockIdx.x;
  const int qt = 7 - (bid & 7), h = (bid >> 3) & 7, b = bid >> 6;
  const int q0 = qt << 6;
  const int t = threadIdx.x, p = t >> 6, tr = t & 63, q = q0 + tr;
  const int nkt = qt + 1;
  const size_t rowbase = (size_t)(b * 512) * 768;

  // Q fragment (fp16 pairs for fdot2)
  const half2v* q2 = (const half2v*)(qkv + rowbase + (size_t)q * 768 + h * 32);
  half2v qh[16];
#pragma unroll
  for (int i = 0; i < 16; i++) qh[i] = q2[i];

  // stage K/V strip: nkt*64 rows x 32, fp16, direct-to-LDS
  for (int c = t; c < nkt * 256; c += 256) {
    const int row = c >> 2, off = (c & 3) << 3;
    const _Float16* kp = qkv + rowbase + (size_t)row * 768 + 256 + h * 32 + off;
    gload16(kp, Ks + c * 8);
    gload16(kp + 256, Vs + c * 8);
  }
  __syncthreads();

  float O[32];
#pragma unroll
  for (int d = 0; d < 32; d++) O[d] = 0.0f;
  float m = -1e30f, lsum = 0.0f;

  for (int kt = p; kt < nkt; kt += 4) {
    const int kb = kt << 6;
    const int rows = (kt == qt) ? (tr + 1) : 64;
    for (int j0 = 0; j0 < rows; j0 += 8) {
      float s[8];
      float mx = -1e30f;
#pragma unroll
      for (int jj = 0; jj < 8; jj++) {
        const half2v* kr = (const half2v*)(Ks + (size_t)(kb + j0 + jj) * 32);
        float a0 = 0.0f, a1 = 0.0f;
#pragma unroll
        for (int d = 0; d < 8; d++) {
          a0 = __builtin_amdgcn_fdot2(qh[d], kr[d], a0, false);
          a1 = __builtin_amdgcn_fdot2(qh[d + 8], kr[d + 8], a1, false);
        }
        const float sc = (a0 + a1) * 0.17677669529663687f;
        s[jj] = (kb + j0 + jj <= q) ? sc : -1e30f;
        mx = fmaxf(mx, s[jj]);
      }
      const float mn = fmaxf(m, mx);
      const float corr = __expf(m - mn);
      lsum *= corr;
#pragma unroll
      for (int d = 0; d < 32; d++) O[d] *= corr;
      m = mn;
#pragma unroll
      for (int jj = 0; jj < 8; jj++) {
        const float pw = __expf(s[jj] - m);
        lsum += pw;
        const half8* vr = (const half8*)(Vs + (size_t)(kb + j0 + jj) * 32);
#pragma unroll
        for (int i = 0; i < 4; i++) {
          half8 vv = vr[i];
#pragma unroll
          for (int d = 0; d < 8; d++) O[i * 8 + d] = fmaf(pw, (float)vv[d], O[i * 8 + d]);
        }
      }
    }
  }

  __syncthreads();  // done with Ks/Vs
  if (p > 0) {
    Om[(p - 1) * 64 + tr] = m;
    Ol[(p - 1) * 64 + tr] = lsum;
    float* od = Os + ((p - 1) * 64 + tr) * 33;
#pragma unroll
    for (int d = 0; d < 32; d++) od[d] = O[d];
  }
  __syncthreads();
  if (p == 0) {
    float mn = m;
#pragma unroll
    for (int pp = 0; pp < 3; pp++) mn = fmaxf(mn, Om[pp * 64 + tr]);
    const float c0 = __expf(m - mn);
    float lt = lsum * c0;
    float cs[3];
#pragma unroll
    for (int pp = 0; pp < 3; pp++) {
      cs[pp] = __expf(Om[pp * 64 + tr] - mn);
      lt += Ol[pp * 64 + tr] * cs[pp];
    }
    const float inv = 1.0f / lt;
    float* op = aout + ((size_t)(b * 512 + q)) * 256 + h * 32;
#pragma unroll
    for (int d = 0; d < 32; d++) {
      float v = O[d] * c0;
#pragma unroll
      for (int pp = 0; pp < 3; pp++) v += Os[(pp * 64 + tr) * 33 + d] * cs[pp];
      op[d] = v * inv;
    }
  }
}

// ---------------------------------------------------------------------------
__global__ __launch_bounds__(256) void reduce_stats_k(const float4* __restrict__ v, int n4,
                                                      float* __restrict__ stats) {
  float s = 0.0f, sq = 0.0f;
  for (int i = blockIdx.x * 256 + threadIdx.x; i < n4; i += gridDim.x * 256) {
    float4 x = v[i];
    s += x.x + x.y + x.z + x.w;
    sq += x.x * x.x + x.y * x.y + x.z * x.z + x.w * x.w;
  }
#pragma unroll
  for (int o = 32; o; o >>= 1) { s += __shfl_xor(s, o); sq += __shfl_xor(sq, o); }
  __shared__ float ss[4], sqq[4];
  const int w = threadIdx.x >> 6;
  if ((threadIdx.x & 63) == 0) { ss[w] = s; sqq[w] = sq; }
  __syncthreads();
  if (threadIdx.x == 0) {
    atomicAdd(&stats[0], ss[0] + ss[1] + ss[2] + ss[3]);
    atomicAdd(&stats[1], sqq[0] + sqq[1] + sqq[2] + sqq[3]);
  }
}

__global__ __launch_bounds__(256) void finalize_k(const float4* __restrict__ enc,
                                                  const float* __restrict__ stats,
                                                  float4* __restrict__ out, int n4, float n) {
  const int i = blockIdx.x * 256 + threadIdx.x;
  if (i >= n4) return;
  const float s = stats[0], q = stats[1];
  const float mean = s / n;
  const float var = (q - s * s / n) / (n - 1.0f);  // ddof=1
  const float inv = rsqrtf(var);
  float4 x = enc[i];
  float4 o;
  o.x = (x.x - mean) * inv + 1e-10f;
  o.y = (x.y - mean) * inv + 1e-10f;
  o.z = (x.z - mean) * inv + 1e-10f;
  o.w = (x.w - mean) * inv + 1e-10f;
  out[i] = o;
}

// ---------------------------------------------------------------------------
extern "C" void kernel_launch(void* const* d_in, const int* in_sizes, int n_in,
                              void* d_out, int out_size, void* d_ws, size_t ws_size,
                              hipStream_t stream) {
  const float* state = (const float*)d_in[0];
  const float* fc1_w = (const float*)d_in[1];
  const float* fc1_b = (const float*)d_in[2];
  const float* fc2_w = (const float*)d_in[3];
  const float* fc2_b = (const float*)d_in[4];
  const float* fc3_w = (const float*)d_in[5];
  const float* fc3_b = (const float*)d_in[6];
  const float* fc4_w = (const float*)d_in[7];
  const float* fc4_b = (const float*)d_in[8];
  const float* fc5_w = (const float*)d_in[9];
  const float* fc5_b = (const float*)d_in[10];
  const float* pre_w = (const float*)d_in[11];
  const float* pre_b = (const float*)d_in[12];
  const float* pos_w = (const float*)d_in[13];
  const float* enc_w = (const float*)d_in[14];
  const float* enc_b = (const float*)d_in[15];
  const float* ln1_g = (const float*)d_in[16];
  const float* ln1_b = (const float*)d_in[17];
  const float* ln2_g = (const float*)d_in[18];
  const float* ln2_b = (const float*)d_in[19];
  const float* res_w1 = (const float*)d_in[20];
  const float* res_b1 = (const float*)d_in[21];
  const float* res_w2 = (const float*)d_in[22];
  const float* res_b2 = (const float*)d_in[23];
  const float* out_w = (const float*)d_in[24];
  const float* out_b = (const float*)d_in[25];

  char* ws = (char*)d_ws;
  _Float16* wbuf = (_Float16*)ws;
  _Float16* bufA = (_Float16*)(ws + 33554432);
  _Float16* bufB = (_Float16*)(ws + 67108864);
  _Float16* xn16 = bufA;                         // 4096*256
  _Float16* qkv16 = bufA + 1048576;              // 4096*768
  _Float16* h16 = bufA + 4194304;                // 4096*1024
  _Float16* x16 = bufA + 8388608;                // 4096*256
  float* xres = (float*)(ws + 67108864 + 4194304);   // 4096*256 fp32
  float* aout = xres + 1048576;                      // 4096*256 fp32
  float* enc32 = aout + 1048576;                     // 4096*128 fp32
  float* stats = enc32 + 524288;                     // 2 floats
  _Float16* encT = (_Float16*)(ws + 67108864 + 16777216);  // 8*768*256
  _Float16* res1T = encT + 1572864;                        // 8*1024*256
  _Float16* res2T = res1T + 2097152;                       // 8*256*1024
  _Float16* outT = res2T + 2097152;                        // 128*256

  const dim3 tb(256);

  // ---- trunk ----
  cast_k<<<16384, tb, 0, stream>>>(state, bufA, 16777216);
  tcast_k<<<dim3(128, 128, 1), tb, 0, stream>>>(fc1_w, wbuf, 4096, 4096);
  gemm_nt<128, 128, 2, 2, 0><<<dim3(32, 32), tb, 0, stream>>>(bufA, wbuf, fc1_b, bufB, nullptr, nullptr, 4096, 4096, 4096);
  tcast_k<<<dim3(64, 128, 1), tb, 0, stream>>>(fc2_w, wbuf, 4096, 2048);
  gemm_nt<128, 128, 2, 2, 0><<<dim3(16, 32), tb, 0, stream>>>(bufB, wbuf, fc2_b, bufA, nullptr, nullptr, 4096, 2048, 4096);
  tcast_k<<<dim3(32, 64, 1), tb, 0, stream>>>(fc3_w, wbuf, 2048, 1024);
  gemm_nt<128, 128, 2, 2, 0><<<dim3(8, 32), tb, 0, stream>>>(bufA, wbuf, fc3_b, bufB, nullptr, nullptr, 4096, 1024, 2048);
  tcast_k<<<dim3(16, 32, 1), tb, 0, stream>>>(fc4_w, wbuf, 1024, 512);
  gemm_nt<128, 64, 4, 1, 0><<<dim3(8, 32), tb, 0, stream>>>(bufB, wbuf, fc4_b, bufA, nullptr, nullptr, 4096, 512, 1024);
  tcast_k<<<dim3(8, 16, 1), tb, 0, stream>>>(fc5_w, wbuf, 512, 256);
  gemm_nt<64, 64, 2, 2, 1><<<dim3(4, 64), tb, 0, stream>>>(bufA, wbuf, fc5_b, bufB, nullptr, nullptr, 4096, 256, 512);
  tcast_k<<<dim3(8, 8, 1), tb, 0, stream>>>(pre_w, wbuf, 256, 256);
  gemm_nt<64, 64, 2, 2, 3><<<dim3(4, 64), tb, 0, stream>>>(bufB, wbuf, pre_b, nullptr, xres, pos_w, 4096, 256, 256);

  // ---- batched block-weight transposes ----
  tcast_k<<<dim3(24, 8, 8), tb, 0, stream>>>(enc_w, encT, 256, 768);
  tcast_k<<<dim3(32, 8, 8), tb, 0, stream>>>(res_w1, res1T, 256, 1024);
  tcast_k<<<dim3(8, 32, 8), tb, 0, stream>>>(res_w2, res2T, 1024, 256);
  tcast_k<<<dim3(4, 8, 1), tb, 0, stream>>>(out_w, outT, 256, 128);

  // ---- transformer blocks ----
  for (int l = 0; l < 8; l++) {
    ln_k<<<1024, tb, 0, stream>>>(xres, ln1_g + l * 256, ln1_b + l * 256, xn16);
    gemm_nt<128, 64, 4, 1, 2><<<dim3(12, 32), tb, 0, stream>>>(xn16, encT + (size_t)l * 196608, enc_b + l * 768,
                                                               qkv16, nullptr, nullptr, 4096, 768, 256);
    attn_k<<<512, tb, 0, stream>>>(qkv16, aout);
    add_ln_k<<<1024, tb, 0, stream>>>(xres, aout, ln2_g + l * 256, ln2_b + l * 256, xres, xn16);
    gemm_nt<128, 128, 2, 2, 4><<<dim3(8, 32), tb, 0, stream>>>(xn16, res1T + (size_t)l * 262144, res_b1 + l * 1024,
                                                               h16, nullptr, nullptr, 4096, 1024, 256);
    gemm_nt<64, 64, 2, 2, 5><<<dim3(4, 64), tb, 0, stream>>>(h16, res2T + (size_t)l * 262144, res_b2 + l * 256,
                                                             x16, xres, xres, 4096, 256, 1024);
  }

  // ---- output projection + global standardization ----
  gemm_nt<64, 64, 2, 2, 6><<<dim3(2, 64), tb, 0, stream>>>(x16, outT, out_b, nullptr, enc32, nullptr, 4096, 128, 256);
  hipMemsetAsync(stats, 0, 2 * sizeof(float), stream);
  reduce_stats_k<<<256, tb, 0, stream>>>((const float4*)enc32, 131072, stats);
  finalize_k<<<512, tb, 0, stream>>>((const float4*)enc32, stats, (float4*)d_out, 131072, 524288.0f);
}